// Round 4
// baseline (1768.429 us; speedup 1.0000x reference)
//
#include <hip/hip_runtime.h>
#include <cstdint>
#include <cstddef>

#define H      640
#define RH     256
#define NE     5
#define NA     40          // NE * rank
#define NTOK   32768
#define SCAL   2.0f        // alpha/rank = 16/8
#define BK     16
#define BM     64          // tokens per block -> grid 512 = exactly 2 blocks/CU
#define NT     (H / BK)    // 40 K-tiles

__device__ __forceinline__ float4 ld4(const float* p) {
    return *reinterpret_cast<const float4*>(p);
}

// async global->LDS, 16B per lane (dest must be linear in lane order)
__device__ __forceinline__ void gload16(const float* g, float* l) {
    __builtin_amdgcn_global_load_lds(
        (const __attribute__((address_space(1))) void*)g,
        (__attribute__((address_space(3))) void*)l, 16, 0, 0);
}

// ---------------------------------------------------------------------------
// Kernel 1: router (x@W1 -> silu -> @W2 -> softmax -> top2) + low = x@A.
// BM=64 tokens/block, BN=256 (full router hidden), BK=16, 256 threads,
// grid=512 = exactly 2 blocks/CU resident (no tail round).
// 2-phase pipelined K-loop (T3-minimum): double-buffered LDS tiles; W1 tile
// staged via global_load_lds dwordx4 (async, 4 wave-issues); x/A tiles
// reg-staged (T14: load at top, ds_write after compute) because xs needs
// row-padding (20 floats) for conflict-free b128 reads. ONE s_barrier +
// vmcnt(0) per iteration, placed AFTER compute so next-tile loads have the
// whole compute phase (~2560 cyc VALU) to land.
// Thread map: tm=tid>>4 (16 groups x 4 tokens), tn=tid&15 (16 col-groups).
// Thread tile: 4 tokens x 16 W1-cols (acc[4][16]) + 4 tokens x 4 low-cols.
// ---------------------------------------------------------------------------
__global__ __launch_bounds__(256, 2)
void k_router(const float* __restrict__ x, const float* __restrict__ W1,
              const float* __restrict__ b1v, const float* __restrict__ W2,
              const float* __restrict__ b2v, const float* __restrict__ A,
              float* __restrict__ route_c, int* __restrict__ route_idx)
{
    __shared__ float ws[2][BK][RH];           // 32 KB, gload_lds dest (linear)
    __shared__ float w2s[RH * NE];            // 5 KB
    __shared__ float b1s[RH];                 // 1 KB
    __shared__ __align__(16) char pool[18432];// 18 KB: loop xs+as_ / epi low+logit
    float (*xs)[BM][20]  = reinterpret_cast<float (*)[BM][20]>(pool);          // 2x5 KB
    float (*as_)[BK][64] = reinterpret_cast<float (*)[BK][64]>(pool + 10240);  // 2x4 KB
    float (*low_lds)[NA] = reinterpret_cast<float (*)[NA]>(pool);              // [64][40]
    float (*logit_lds)[8]= reinterpret_cast<float (*)[8]>(pool + 10240);       // [64][8]

    const int tid  = threadIdx.x;
    const int row0 = blockIdx.x * BM;
    const int tm   = tid >> 4;
    const int tn   = tid & 15;
    const int lane = tid & 63;
    const int wv   = tid >> 6;

    // per-thread staging constants (hoisted)
    const int xrow = tid >> 2, xc = tid & 3;             // x tile: row, f4-col
    const int arow = tid / 10, ac4 = tid % 10;           // A tile (tid<160)
    const int ae = ac4 >> 1, ar0 = (ac4 & 1) * 4;
    const float* xsrc = x + (size_t)(row0 + xrow) * H + xc * 4;
    const float* asrc = A + ((size_t)ae * H + arow) * 8 + ar0;

    for (int i = tid; i < RH * NE; i += 256) w2s[i] = W2[i];
    if (tid < RH) b1s[tid] = b1v[tid];

    // ---- prologue: stage tile 0 into buffer 0 ----
    {
        const int c0 = wv * 4;
        #pragma unroll
        for (int i = 0; i < 4; i++)
            gload16(W1 + (size_t)(c0 + i) * RH + lane * 4, &ws[0][c0 + i][lane * 4]);
        float4 xr = ld4(xsrc);
        *reinterpret_cast<float4*>(&xs[0][xrow][xc * 4]) = xr;
        if (tid < 160) {
            float4 ar = ld4(asrc);
            *reinterpret_cast<float4*>(&as_[0][arow][ac4 * 4]) = ar;
        }
    }
    asm volatile("s_waitcnt vmcnt(0) lgkmcnt(0)" ::: "memory");
    __builtin_amdgcn_s_barrier();

    float acc[4][16];
    #pragma unroll
    for (int j = 0; j < 4; j++)
        #pragma unroll
        for (int c = 0; c < 16; c++) acc[j][c] = 0.f;
    float accl[4][4];
    #pragma unroll
    for (int j = 0; j < 4; j++)
        #pragma unroll
        for (int c = 0; c < 4; c++) accl[j][c] = 0.f;

    for (int t = 0; t < NT; ++t) {
        const int bc = t & 1, bn = bc ^ 1;
        const int k0n = (t + 1) * BK;
        float4 xr, ar;
        const bool more = (t + 1 < NT);
        if (more) {
            const int c0 = wv * 4;
            const float* wp = W1 + (size_t)k0n * RH + lane * 4;
            #pragma unroll
            for (int i = 0; i < 4; i++)
                gload16(wp + (size_t)(c0 + i) * RH, &ws[bn][c0 + i][lane * 4]);
            xr = ld4(xsrc + k0n);
            if (tid < 160) ar = ld4(asrc + (size_t)k0n * 8);
        }

        // ---- compute tile t from buffer bc ----
        const float* wsb = &ws[bc][0][0];
        const float* xsb = &xs[bc][0][0];
        const float* asb = &as_[bc][0][0];
        #pragma unroll
        for (int kk4 = 0; kk4 < BK; kk4 += 4) {
            float4 xa[4];
            #pragma unroll
            for (int j = 0; j < 4; j++)
                xa[j] = *reinterpret_cast<const float4*>(xsb + (4 * tm + j) * 20 + kk4);
            #pragma unroll
            for (int u = 0; u < 4; u++) {
                float bb[16];
                #pragma unroll
                for (int q = 0; q < 4; q++)
                    *reinterpret_cast<float4*>(&bb[q * 4]) =
                        *reinterpret_cast<const float4*>(wsb + (kk4 + u) * RH + (tn + 16 * q) * 4);
                float lb[4];
                *reinterpret_cast<float4*>(lb) =
                    *reinterpret_cast<const float4*>(asb + (kk4 + u) * 64 + tn * 4);
                #pragma unroll
                for (int j = 0; j < 4; j++) {
                    float av = (u == 0) ? xa[j].x : (u == 1) ? xa[j].y
                             : (u == 2) ? xa[j].z : xa[j].w;
                    #pragma unroll
                    for (int c = 0; c < 16; c++)
                        acc[j][c] = fmaf(av, bb[c], acc[j][c]);
                    #pragma unroll
                    for (int c = 0; c < 4; c++)
                        accl[j][c] = fmaf(av, lb[c], accl[j][c]);
                }
            }
        }

        if (more) {
            *reinterpret_cast<float4*>(&xs[bn][xrow][xc * 4]) = xr;
            if (tid < 160)
                *reinterpret_cast<float4*>(&as_[bn][arow][ac4 * 4]) = ar;
        }
        asm volatile("s_waitcnt vmcnt(0) lgkmcnt(0)" ::: "memory");
        __builtin_amdgcn_s_barrier();
    }

    // ---- epilogue (pool now aliased to low_lds / logit_lds) ----
    if (tn < 10) {
        #pragma unroll
        for (int j = 0; j < 4; j++)
            *reinterpret_cast<float4*>(&low_lds[4 * tm + j][tn * 4]) =
                *reinterpret_cast<float4*>(&accl[j][0]);
    }

    float part[4][5];
    #pragma unroll
    for (int j = 0; j < 4; j++)
        #pragma unroll
        for (int e = 0; e < 5; e++) part[j][e] = 0.f;

    #pragma unroll
    for (int q = 0; q < 4; q++)
        #pragma unroll
        for (int i4 = 0; i4 < 4; i4++) {
            int col = (tn + 16 * q) * 4 + i4;
            float bbias = b1s[col];
            float w2r[5];
            #pragma unroll
            for (int e = 0; e < 5; e++) w2r[e] = w2s[col * 5 + e];
            #pragma unroll
            for (int j = 0; j < 4; j++) {
                float v = acc[j][q * 4 + i4] + bbias;
                float s = __fdividef(v, 1.f + __expf(-v));   // silu
                #pragma unroll
                for (int e = 0; e < 5; e++) part[j][e] = fmaf(s, w2r[e], part[j][e]);
            }
        }

    #pragma unroll
    for (int j = 0; j < 4; j++)
        #pragma unroll
        for (int e = 0; e < 5; e++) {
            float v = part[j][e];
            v += __shfl_xor(v, 1);
            v += __shfl_xor(v, 2);
            v += __shfl_xor(v, 4);
            v += __shfl_xor(v, 8);
            part[j][e] = v;
        }

    if (tn == 0) {
        #pragma unroll
        for (int j = 0; j < 4; j++)
            #pragma unroll
            for (int e = 0; e < 5; e++) logit_lds[4 * tm + j][e] = part[j][e];
    }
    __syncthreads();

    if (tid < BM) {
        const int tk = tid;
        float l0 = logit_lds[tk][0] + b2v[0];
        float l1 = logit_lds[tk][1] + b2v[1];
        float l2 = logit_lds[tk][2] + b2v[2];
        float l3 = logit_lds[tk][3] + b2v[3];
        float l4 = logit_lds[tk][4] + b2v[4];
        int   i0 = 0;  float m0 = l0;
        int   i1 = -1; float m1 = -3.4e38f;
        if (l1 > m0) { m1 = m0; i1 = i0; m0 = l1; i0 = 1; } else if (l1 > m1) { m1 = l1; i1 = 1; }
        if (l2 > m0) { m1 = m0; i1 = i0; m0 = l2; i0 = 2; } else if (l2 > m1) { m1 = l2; i1 = 2; }
        if (l3 > m0) { m1 = m0; i1 = i0; m0 = l3; i0 = 3; } else if (l3 > m1) { m1 = l3; i1 = 3; }
        if (l4 > m0) { m1 = m0; i1 = i0; m0 = l4; i0 = 4; } else if (l4 > m1) { m1 = l4; i1 = 4; }
        float w1r = __expf(m1 - m0);
        float inv = __fdividef(1.f, 1.f + w1r);
        float c0 = inv * SCAL;
        float c1 = w1r * inv * SCAL;
        int gt = row0 + tk;
        #pragma unroll
        for (int r4 = 0; r4 < 2; r4++) {
            float4 v0 = ld4(&low_lds[tk][i0 * 8 + r4 * 4]);
            v0.x *= c0; v0.y *= c0; v0.z *= c0; v0.w *= c0;
            *reinterpret_cast<float4*>(&route_c[(size_t)gt * 16 + r4 * 4]) = v0;
            float4 v1 = ld4(&low_lds[tk][i1 * 8 + r4 * 4]);
            v1.x *= c1; v1.y *= c1; v1.z *= c1; v1.w *= c1;
            *reinterpret_cast<float4*>(&route_c[(size_t)gt * 16 + 8 + r4 * 4]) = v1;
        }
        route_idx[gt * 2 + 0] = i0;
        route_idx[gt * 2 + 1] = i1;
    }
}

// ---------------------------------------------------------------------------
// Kernel 2: out[t] = base[t] + sum_j c[t][j] * Bm_row[idx_j][:]
// All of Bm (40x640 f32 = 102.4 KB) staged in LDS. 512 thr (8 waves), one
// wave per token at a time; grid = 256 blocks * 128 tokens.
// ---------------------------------------------------------------------------
__global__ __launch_bounds__(512)
void k_combine(const float* __restrict__ base, const float* __restrict__ Bm,
               const float* __restrict__ route_c, const int* __restrict__ route_idx,
               float* __restrict__ out)
{
    __shared__ float bs[NA][H];
    const int tid = threadIdx.x;
    for (int i4 = tid; i4 < NA * H / 4; i4 += 512)
        reinterpret_cast<float4*>(&bs[0][0])[i4] = reinterpret_cast<const float4*>(Bm)[i4];
    __syncthreads();

    const int w    = tid >> 6;
    const int lane = tid & 63;

    for (int it = 0; it < 16; it++) {
        int t = blockIdx.x * 128 + w * 16 + it;
        t = __builtin_amdgcn_readfirstlane(t);
        const int e0 = route_idx[t * 2 + 0];
        const int e1 = route_idx[t * 2 + 1];
        float cc[16];
        #pragma unroll
        for (int q = 0; q < 4; q++)
            *reinterpret_cast<float4*>(&cc[q * 4]) = ld4(route_c + (size_t)t * 16 + q * 4);

        const float* brow0 = &bs[e0 * 8][0];
        const float* brow1 = &bs[e1 * 8][0];
        const float* bp = base + (size_t)t * H;
        float*       op = out  + (size_t)t * H;

        #pragma unroll
        for (int i = 0; i < 2; i++) {
            int h = i * 256 + lane * 4;
            float4 a = ld4(bp + h);
            #pragma unroll
            for (int j = 0; j < 8; j++) {
                float4 bv = *reinterpret_cast<const float4*>(brow0 + j * H + h);
                a.x = fmaf(cc[j], bv.x, a.x); a.y = fmaf(cc[j], bv.y, a.y);
                a.z = fmaf(cc[j], bv.z, a.z); a.w = fmaf(cc[j], bv.w, a.w);
            }
            #pragma unroll
            for (int j = 0; j < 8; j++) {
                float4 bv = *reinterpret_cast<const float4*>(brow1 + j * H + h);
                a.x = fmaf(cc[8 + j], bv.x, a.x); a.y = fmaf(cc[8 + j], bv.y, a.y);
                a.z = fmaf(cc[8 + j], bv.z, a.z); a.w = fmaf(cc[8 + j], bv.w, a.w);
            }
            *reinterpret_cast<float4*>(op + h) = a;
        }
        {
            int h = 512 + lane * 2;
            float2 a = *reinterpret_cast<const float2*>(bp + h);
            #pragma unroll
            for (int j = 0; j < 8; j++) {
                float2 bv = *reinterpret_cast<const float2*>(brow0 + j * H + h);
                a.x = fmaf(cc[j], bv.x, a.x); a.y = fmaf(cc[j], bv.y, a.y);
            }
            #pragma unroll
            for (int j = 0; j < 8; j++) {
                float2 bv = *reinterpret_cast<const float2*>(brow1 + j * H + h);
                a.x = fmaf(cc[8 + j], bv.x, a.x); a.y = fmaf(cc[8 + j], bv.y, a.y);
            }
            *reinterpret_cast<float2*>(op + h) = a;
        }
    }
}

extern "C" void kernel_launch(void* const* d_in, const int* in_sizes, int n_in,
                              void* d_out, int out_size, void* d_ws, size_t ws_size,
                              hipStream_t stream)
{
    const float* x  = (const float*)d_in[0];
    const float* bo = (const float*)d_in[1];
    const float* W1 = (const float*)d_in[2];
    const float* b1 = (const float*)d_in[3];
    const float* W2 = (const float*)d_in[4];
    const float* b2 = (const float*)d_in[5];
    const float* A  = (const float*)d_in[6];
    const float* Bm = (const float*)d_in[7];
    float* out = (float*)d_out;

    float* route_c   = (float*)d_ws;                                   // 32768*16 f32 = 2 MB
    int*   route_idx = (int*)((char*)d_ws + (size_t)NTOK * 16 * 4);    // 32768*2 i32 = 256 KB

    k_router<<<dim3(NTOK / BM), dim3(256), 0, stream>>>(
        x, W1, b1, W2, b2, A, route_c, route_idx);
    k_combine<<<dim3(256), dim3(512), 0, stream>>>(
        bo, Bm, route_c, route_idx, out);
}

// Round 5
// 316.889 us; speedup vs baseline: 5.5806x; 5.5806x over previous
//
#include <hip/hip_runtime.h>
#include <cstdint>
#include <cstddef>

#define H      640
#define RH     256
#define NE     5
#define NA     40          // NE * rank
#define NTOK   32768
#define SCAL   2.0f        // alpha/rank = 16/8
#define BK     16
#define BM     64          // tokens per block -> grid 512 = exactly 2 blocks/CU
#define NT     (H / BK)    // 40 K-tiles

__device__ __forceinline__ float4 ld4(const float* p) {
    return *reinterpret_cast<const float4*>(p);
}

// async global->LDS, 16B per lane: dest = wave-uniform base + lane*16
__device__ __forceinline__ void gload16(const float* g, float* lds_base) {
    __builtin_amdgcn_global_load_lds(
        (const __attribute__((address_space(1))) void*)g,
        (__attribute__((address_space(3))) void*)lds_base, 16, 0, 0);
}

// ---------------------------------------------------------------------------
// Kernel 1: router (x@W1 -> silu -> @W2 -> softmax -> top2) + low = x@A.
// BM=64 tokens/block, BN=256 (full router hidden), BK=16, 256 threads,
// grid=512 = exactly 2 blocks/CU. 2-phase pipelined K-loop: dbuf LDS tiles;
// W1 via global_load_lds dwordx4; x/A reg-staged (T14). ONE s_barrier +
// vmcnt(0) per iteration, after compute, so next-tile loads land under the
// ~2560-cyc FMA phase. Thread tile: 4 tokens x 16 W1-cols + 4 tok x 4 low.
// NOTE: __launch_bounds__(256) with NO min-waves arg -- round 4's 128-VGPR
// cap spilled the 80-reg accumulator to scratch (5 GB WRITE_SIZE).
// ---------------------------------------------------------------------------
__global__ __launch_bounds__(256)
void k_router(const float* __restrict__ x, const float* __restrict__ W1,
              const float* __restrict__ b1v, const float* __restrict__ W2,
              const float* __restrict__ b2v, const float* __restrict__ A,
              float* __restrict__ route_c, int* __restrict__ route_idx)
{
    __shared__ float ws[2][BK][RH];           // 32 KB, gload_lds dest (linear)
    __shared__ float w2s[RH * NE];            // 5 KB
    __shared__ float b1s[RH];                 // 1 KB
    __shared__ __align__(16) char pool[18432];// 18 KB: loop xs+as_ / epi low+logit
    float (*xs)[BM][20]  = reinterpret_cast<float (*)[BM][20]>(pool);          // 2x5 KB
    float (*as_)[BK][64] = reinterpret_cast<float (*)[BK][64]>(pool + 10240);  // 2x4 KB
    float (*low_lds)[NA] = reinterpret_cast<float (*)[NA]>(pool);              // [64][40]
    float (*logit_lds)[8]= reinterpret_cast<float (*)[8]>(pool + 10240);       // [64][8]

    const int tid  = threadIdx.x;
    const int row0 = blockIdx.x * BM;
    const int tm   = tid >> 4;
    const int tn   = tid & 15;
    const int lane = tid & 63;
    const int wv   = tid >> 6;

    // per-thread staging constants (hoisted)
    const int xrow = tid >> 2, xc = tid & 3;             // x tile: row, f4-col
    const int arow = tid / 10, ac4 = tid % 10;           // A tile (tid<160)
    const int ae = ac4 >> 1, ar0 = (ac4 & 1) * 4;
    const float* xsrc = x + (size_t)(row0 + xrow) * H + xc * 4;
    const float* asrc = A + ((size_t)ae * H + arow) * 8 + ar0;

    for (int i = tid; i < RH * NE; i += 256) w2s[i] = W2[i];
    if (tid < RH) b1s[tid] = b1v[tid];

    // ---- prologue: stage tile 0 into buffer 0 ----
    {
        const int c0 = wv * 4;
        #pragma unroll
        for (int i = 0; i < 4; i++)
            gload16(W1 + (size_t)(c0 + i) * RH + lane * 4, &ws[0][c0 + i][0]);
        float4 xr = ld4(xsrc);
        *reinterpret_cast<float4*>(&xs[0][xrow][xc * 4]) = xr;
        if (tid < 160) {
            float4 ar = ld4(asrc);
            *reinterpret_cast<float4*>(&as_[0][arow][ac4 * 4]) = ar;
        }
    }
    asm volatile("s_waitcnt vmcnt(0) lgkmcnt(0)" ::: "memory");
    __builtin_amdgcn_s_barrier();

    float acc[4][16];
    #pragma unroll
    for (int j = 0; j < 4; j++)
        #pragma unroll
        for (int c = 0; c < 16; c++) acc[j][c] = 0.f;
    float accl[4][4];
    #pragma unroll
    for (int j = 0; j < 4; j++)
        #pragma unroll
        for (int c = 0; c < 4; c++) accl[j][c] = 0.f;

    for (int t = 0; t < NT; ++t) {
        const int bc = t & 1, bn = bc ^ 1;
        const int k0n = (t + 1) * BK;
        float4 xr, ar;
        const bool more = (t + 1 < NT);
        if (more) {
            const int c0 = wv * 4;
            const float* wp = W1 + (size_t)k0n * RH + lane * 4;
            #pragma unroll
            for (int i = 0; i < 4; i++)
                gload16(wp + (size_t)(c0 + i) * RH, &ws[bn][c0 + i][0]);
            xr = ld4(xsrc + k0n);
            if (tid < 160) ar = ld4(asrc + (size_t)k0n * 8);
        }

        // ---- compute tile t from buffer bc ----
        const float* wsb = &ws[bc][0][0];
        const float* xsb = &xs[bc][0][0];
        const float* asb = &as_[bc][0][0];
        #pragma unroll
        for (int kk4 = 0; kk4 < BK; kk4 += 4) {
            float4 xa[4];
            #pragma unroll
            for (int j = 0; j < 4; j++)
                xa[j] = *reinterpret_cast<const float4*>(xsb + (4 * tm + j) * 20 + kk4);
            #pragma unroll
            for (int u = 0; u < 4; u++) {
                float bb[16];
                #pragma unroll
                for (int q = 0; q < 4; q++)
                    *reinterpret_cast<float4*>(&bb[q * 4]) =
                        *reinterpret_cast<const float4*>(wsb + (kk4 + u) * RH + (tn + 16 * q) * 4);
                float lb[4];
                *reinterpret_cast<float4*>(lb) =
                    *reinterpret_cast<const float4*>(asb + (kk4 + u) * 64 + tn * 4);
                #pragma unroll
                for (int j = 0; j < 4; j++) {
                    float av = (u == 0) ? xa[j].x : (u == 1) ? xa[j].y
                             : (u == 2) ? xa[j].z : xa[j].w;
                    #pragma unroll
                    for (int c = 0; c < 16; c++)
                        acc[j][c] = fmaf(av, bb[c], acc[j][c]);
                    #pragma unroll
                    for (int c = 0; c < 4; c++)
                        accl[j][c] = fmaf(av, lb[c], accl[j][c]);
                }
            }
        }

        if (more) {
            *reinterpret_cast<float4*>(&xs[bn][xrow][xc * 4]) = xr;
            if (tid < 160)
                *reinterpret_cast<float4*>(&as_[bn][arow][ac4 * 4]) = ar;
        }
        asm volatile("s_waitcnt vmcnt(0) lgkmcnt(0)" ::: "memory");
        __builtin_amdgcn_s_barrier();
    }

    // ---- epilogue (pool now aliased to low_lds / logit_lds) ----
    if (tn < 10) {
        #pragma unroll
        for (int j = 0; j < 4; j++)
            *reinterpret_cast<float4*>(&low_lds[4 * tm + j][tn * 4]) =
                *reinterpret_cast<float4*>(&accl[j][0]);
    }

    float part[4][5];
    #pragma unroll
    for (int j = 0; j < 4; j++)
        #pragma unroll
        for (int e = 0; e < 5; e++) part[j][e] = 0.f;

    #pragma unroll
    for (int q = 0; q < 4; q++)
        #pragma unroll
        for (int i4 = 0; i4 < 4; i4++) {
            int col = (tn + 16 * q) * 4 + i4;
            float bbias = b1s[col];
            float w2r[5];
            #pragma unroll
            for (int e = 0; e < 5; e++) w2r[e] = w2s[col * 5 + e];
            #pragma unroll
            for (int j = 0; j < 4; j++) {
                float v = acc[j][q * 4 + i4] + bbias;
                float s = __fdividef(v, 1.f + __expf(-v));   // silu
                #pragma unroll
                for (int e = 0; e < 5; e++) part[j][e] = fmaf(s, w2r[e], part[j][e]);
            }
        }

    #pragma unroll
    for (int j = 0; j < 4; j++)
        #pragma unroll
        for (int e = 0; e < 5; e++) {
            float v = part[j][e];
            v += __shfl_xor(v, 1);
            v += __shfl_xor(v, 2);
            v += __shfl_xor(v, 4);
            v += __shfl_xor(v, 8);
            part[j][e] = v;
        }

    if (tn == 0) {
        #pragma unroll
        for (int j = 0; j < 4; j++)
            #pragma unroll
            for (int e = 0; e < 5; e++) logit_lds[4 * tm + j][e] = part[j][e];
    }
    __syncthreads();

    if (tid < BM) {
        const int tk = tid;
        float l0 = logit_lds[tk][0] + b2v[0];
        float l1 = logit_lds[tk][1] + b2v[1];
        float l2 = logit_lds[tk][2] + b2v[2];
        float l3 = logit_lds[tk][3] + b2v[3];
        float l4 = logit_lds[tk][4] + b2v[4];
        int   i0 = 0;  float m0 = l0;
        int   i1 = -1; float m1 = -3.4e38f;
        if (l1 > m0) { m1 = m0; i1 = i0; m0 = l1; i0 = 1; } else if (l1 > m1) { m1 = l1; i1 = 1; }
        if (l2 > m0) { m1 = m0; i1 = i0; m0 = l2; i0 = 2; } else if (l2 > m1) { m1 = l2; i1 = 2; }
        if (l3 > m0) { m1 = m0; i1 = i0; m0 = l3; i0 = 3; } else if (l3 > m1) { m1 = l3; i1 = 3; }
        if (l4 > m0) { m1 = m0; i1 = i0; m0 = l4; i0 = 4; } else if (l4 > m1) { m1 = l4; i1 = 4; }
        float w1r = __expf(m1 - m0);
        float inv = __fdividef(1.f, 1.f + w1r);
        float c0 = inv * SCAL;
        float c1 = w1r * inv * SCAL;
        int gt = row0 + tk;
        #pragma unroll
        for (int r4 = 0; r4 < 2; r4++) {
            float4 v0 = ld4(&low_lds[tk][i0 * 8 + r4 * 4]);
            v0.x *= c0; v0.y *= c0; v0.z *= c0; v0.w *= c0;
            *reinterpret_cast<float4*>(&route_c[(size_t)gt * 16 + r4 * 4]) = v0;
            float4 v1 = ld4(&low_lds[tk][i1 * 8 + r4 * 4]);
            v1.x *= c1; v1.y *= c1; v1.z *= c1; v1.w *= c1;
            *reinterpret_cast<float4*>(&route_c[(size_t)gt * 16 + 8 + r4 * 4]) = v1;
        }
        route_idx[gt * 2 + 0] = i0;
        route_idx[gt * 2 + 1] = i1;
    }
}

// ---------------------------------------------------------------------------
// Kernel 2: out[t] = base[t] + sum_j c[t][j] * Bm_row[idx_j][:]
// All of Bm (40x640 f32 = 102.4 KB) staged in LDS. 512 thr (8 waves), one
// wave per token at a time; grid = 256 blocks * 128 tokens.
// ---------------------------------------------------------------------------
__global__ __launch_bounds__(512)
void k_combine(const float* __restrict__ base, const float* __restrict__ Bm,
               const float* __restrict__ route_c, const int* __restrict__ route_idx,
               float* __restrict__ out)
{
    __shared__ float bs[NA][H];
    const int tid = threadIdx.x;
    for (int i4 = tid; i4 < NA * H / 4; i4 += 512)
        reinterpret_cast<float4*>(&bs[0][0])[i4] = reinterpret_cast<const float4*>(Bm)[i4];
    __syncthreads();

    const int w    = tid >> 6;
    const int lane = tid & 63;

    for (int it = 0; it < 16; it++) {
        int t = blockIdx.x * 128 + w * 16 + it;
        t = __builtin_amdgcn_readfirstlane(t);
        const int e0 = route_idx[t * 2 + 0];
        const int e1 = route_idx[t * 2 + 1];
        float cc[16];
        #pragma unroll
        for (int q = 0; q < 4; q++)
            *reinterpret_cast<float4*>(&cc[q * 4]) = ld4(route_c + (size_t)t * 16 + q * 4);

        const float* brow0 = &bs[e0 * 8][0];
        const float* brow1 = &bs[e1 * 8][0];
        const float* bp = base + (size_t)t * H;
        float*       op = out  + (size_t)t * H;

        #pragma unroll
        for (int i = 0; i < 2; i++) {
            int h = i * 256 + lane * 4;
            float4 a = ld4(bp + h);
            #pragma unroll
            for (int j = 0; j < 8; j++) {
                float4 bv = *reinterpret_cast<const float4*>(brow0 + j * H + h);
                a.x = fmaf(cc[j], bv.x, a.x); a.y = fmaf(cc[j], bv.y, a.y);
                a.z = fmaf(cc[j], bv.z, a.z); a.w = fmaf(cc[j], bv.w, a.w);
            }
            #pragma unroll
            for (int j = 0; j < 8; j++) {
                float4 bv = *reinterpret_cast<const float4*>(brow1 + j * H + h);
                a.x = fmaf(cc[8 + j], bv.x, a.x); a.y = fmaf(cc[8 + j], bv.y, a.y);
                a.z = fmaf(cc[8 + j], bv.z, a.z); a.w = fmaf(cc[8 + j], bv.w, a.w);
            }
            *reinterpret_cast<float4*>(op + h) = a;
        }
        {
            int h = 512 + lane * 2;
            float2 a = *reinterpret_cast<const float2*>(bp + h);
            #pragma unroll
            for (int j = 0; j < 8; j++) {
                float2 bv = *reinterpret_cast<const float2*>(brow0 + j * H + h);
                a.x = fmaf(cc[j], bv.x, a.x); a.y = fmaf(cc[j], bv.y, a.y);
            }
            #pragma unroll
            for (int j = 0; j < 8; j++) {
                float2 bv = *reinterpret_cast<const float2*>(brow1 + j * H + h);
                a.x = fmaf(cc[8 + j], bv.x, a.x); a.y = fmaf(cc[8 + j], bv.y, a.y);
            }
            *reinterpret_cast<float2*>(op + h) = a;
        }
    }
}

extern "C" void kernel_launch(void* const* d_in, const int* in_sizes, int n_in,
                              void* d_out, int out_size, void* d_ws, size_t ws_size,
                              hipStream_t stream)
{
    const float* x  = (const float*)d_in[0];
    const float* bo = (const float*)d_in[1];
    const float* W1 = (const float*)d_in[2];
    const float* b1 = (const float*)d_in[3];
    const float* W2 = (const float*)d_in[4];
    const float* b2 = (const float*)d_in[5];
    const float* A  = (const float*)d_in[6];
    const float* Bm = (const float*)d_in[7];
    float* out = (float*)d_out;

    float* route_c   = (float*)d_ws;                                   // 32768*16 f32 = 2 MB
    int*   route_idx = (int*)((char*)d_ws + (size_t)NTOK * 16 * 4);    // 32768*2 i32 = 256 KB

    k_router<<<dim3(NTOK / BM), dim3(256), 0, stream>>>(
        x, W1, b1, W2, b2, A, route_c, route_idx);
    k_combine<<<dim3(256), dim3(512), 0, stream>>>(
        bo, Bm, route_c, route_idx, out);
}